// Round 2
// 735.153 us; speedup vs baseline: 1.0196x; 1.0196x over previous
//
#include <hip/hip_runtime.h>

// Problem constants (match reference)
#define C 8            // NUM_CHIPS
#define S 2048         // SEQ
#define H 1024         // HIDDEN
#define K 8            // TOPK
#define E 64           // N_ROUTED_EXPERTS
#define MT 2560        // MAX_TOK
#define ML 8           // METADATA_LEN
#define N (S * K)      // assignments per chip = 16384
#define SEG 256        // assignments per histogram segment
#define NSEG (N / SEG) // 64 segments per chip
#define CS (C * NSEG)  // 512 (chip,seg) slots in chip-major scan order
#define DISP_ELEMS ((long long)E * MT * H)   // 167,772,160
#define META_ELEMS ((long long)E * MT * ML)  // 1,310,720

// Native 16-byte vector (works with __builtin_nontemporal_store, unlike
// HIP's float4 class type).
typedef float f4 __attribute__((ext_vector_type(4)));

// ---------------------------------------------------------------------------
// K1: per-(chip,segment) expert histogram. blockIdx = c*NSEG + seg.
// Counts stored TRANSPOSED as [E][CS] so the per-expert scan reads coalesced.
__global__ __launch_bounds__(SEG) void hist_kernel(const int* __restrict__ idx,
                                                   int* __restrict__ seg_counts) {
    __shared__ int hist[E];
    const int b = blockIdx.x;
    const int t = threadIdx.x;
    if (t < E) hist[t] = 0;
    __syncthreads();
    atomicAdd(&hist[idx[b * SEG + t]], 1);
    __syncthreads();
    if (t < E) seg_counts[t * CS + b] = hist[t];
}

// ---------------------------------------------------------------------------
// K2: PARALLEL exclusive scan. One block per expert (64 blocks), 512 threads,
// Hillis-Steele over the 512 (chip,seg) slots in LDS. Replaces the old
// 1-block/64-thread serial kernel whose 512-long dependent load chain
// (cross-XCD L2 sourcing) idled 255 CUs.
__global__ __launch_bounds__(CS) void scan_kernel(const int* __restrict__ seg_counts,
                                                  int* __restrict__ seg_base,
                                                  int* __restrict__ tokens_total,
                                                  float* __restrict__ tpe_out) {
    __shared__ int buf[CS];
    const int e = blockIdx.x;   // 0..63
    const int t = threadIdx.x;  // 0..511
    const int v = seg_counts[e * CS + t];
    buf[t] = v;
    __syncthreads();
#pragma unroll
    for (int off = 1; off < CS; off <<= 1) {
        const int add = (t >= off) ? buf[t - off] : 0;
        __syncthreads();
        buf[t] += add;
        __syncthreads();
    }
    const int incl = buf[t];
    seg_base[e * CS + t] = incl - v;  // exclusive prefix (chip-major order)
    if (t == CS - 1) {
        tokens_total[e] = incl;
        tpe_out[e] = (float)incl;     // third output (tokens_per_expert)
    }
}

// ---------------------------------------------------------------------------
// K3: stable within-segment rank + final destination slot.
__global__ __launch_bounds__(SEG) void rank_kernel(const int* __restrict__ idx,
                                                   const int* __restrict__ seg_base,
                                                   int* __restrict__ dest) {
    __shared__ int se[SEG];
    const int b = blockIdx.x;
    const int t = threadIdx.x;
    const int e = idx[b * SEG + t];
    se[t] = e;
    __syncthreads();
    int rank = 0;
    for (int j = 0; j < t; ++j) rank += (se[j] == e);
    dest[b * SEG + t] = e * MT + seg_base[e * CS + b] + rank;
}

// ---------------------------------------------------------------------------
// K4: scatter. One block per (chip, token): read the 4KB row once, write it
// to its 8 destination rows (each a fully coalesced 4KB burst) + metadata.
// Row writes are nontemporal: 537 MB streaming, never re-read — keep it out
// of the 4 MiB/XCD L2s.
__global__ __launch_bounds__(256) void scatter_kernel(const float* __restrict__ x,
                                                      const float* __restrict__ w,
                                                      const int* __restrict__ dest,
                                                      float* __restrict__ out) {
    __shared__ int d8[K];
    __shared__ float w8[K];
    const int b = blockIdx.x;       // c*S + tok
    const int t = threadIdx.x;      // 0..255
    const int c = b >> 11;          // / S
    const int tok = b & (S - 1);
    if (t < K) {
        d8[t] = dest[c * N + tok * K + t];
        w8[t] = w[b * K + t];
    }
    __syncthreads();

    const f4 v = ((const f4*)x)[(long long)b * (H / 4) + t];
    f4* o4 = (f4*)out;
#pragma unroll
    for (int k = 0; k < K; ++k) {
        __builtin_nontemporal_store(v, &o4[(long long)d8[k] * (H / 4) + t]);
    }

    // metadata rows: [chip, token, topk, expert, weight, 0, 0, 0]
    float* meta = out + DISP_ELEMS;
    if (t < K * ML) {
        const int k = t >> 3;
        const int j = t & 7;
        const int d = d8[k];
        float val = 0.0f;
        if (j == 0) val = (float)c;
        else if (j == 1) val = (float)tok;
        else if (j == 2) val = (float)k;
        else if (j == 3) val = (float)(d / MT); // recover expert id
        else if (j == 4) val = w8[k];
        meta[(long long)d * ML + j] = val;
    }
}

// ---------------------------------------------------------------------------
// K5: fill unused slots — dispatched rows -> 0, metadata rows -> -1.
// d_out is poisoned before every timed launch, so every byte must be
// written each call. One block per (expert, row); written rows early-exit.
__global__ __launch_bounds__(256) void fill_kernel(const int* __restrict__ tokens_total,
                                                   float* __restrict__ out) {
    const int b = blockIdx.x;  // e*MT + r
    const int e = b / MT;
    const int r = b - e * MT;
    if (r < tokens_total[e]) return;
    const int t = threadIdx.x;
    f4* o4 = (f4*)out;
    const f4 z = {0.f, 0.f, 0.f, 0.f};
    __builtin_nontemporal_store(z, &o4[(long long)b * (H / 4) + t]);
    if (t < ML) {
        float* meta = out + DISP_ELEMS;
        meta[(long long)b * ML + t] = -1.0f;
    }
}

// ---------------------------------------------------------------------------
extern "C" void kernel_launch(void* const* d_in, const int* in_sizes, int n_in,
                              void* d_out, int out_size, void* d_ws, size_t ws_size,
                              hipStream_t stream) {
    const float* x  = (const float*)d_in[0];   // (C,S,H) f32
    const float* w  = (const float*)d_in[1];   // (C,S,K) f32
    const int* idx  = (const int*)d_in[2];     // (C,S,K) i32
    float* out = (float*)d_out;

    // workspace layout (ints): seg_counts | seg_base | dest | tokens_total
    int* ws = (int*)d_ws;
    int* seg_counts   = ws;                       // E*CS = 32768
    int* seg_base     = ws + E * CS;              // 32768
    int* dest         = ws + 2 * E * CS;          // C*N = 131072
    int* tokens_total = ws + 2 * E * CS + C * N;  // 64

    float* tpe_out = out + DISP_ELEMS + META_ELEMS;  // third output chunk

    hipLaunchKernelGGL(hist_kernel, dim3(CS), dim3(SEG), 0, stream, idx, seg_counts);
    hipLaunchKernelGGL(scan_kernel, dim3(E), dim3(CS), 0, stream,
                       seg_counts, seg_base, tokens_total, tpe_out);
    hipLaunchKernelGGL(rank_kernel, dim3(CS), dim3(SEG), 0, stream, idx, seg_base, dest);
    hipLaunchKernelGGL(scatter_kernel, dim3(C * S), dim3(256), 0, stream, x, w, dest, out);
    hipLaunchKernelGGL(fill_kernel, dim3(E * MT), dim3(256), 0, stream, tokens_total, out);
}